// Round 1
// baseline (1919.007 us; speedup 1.0000x reference)
//
#include <hip/hip_runtime.h>
#include <math.h>

#define D_MODEL 1024
#define D_STATE 16
#define D_CONV  4
#define D_INNER 2048
#define BATCH   2
#define SEQ     2048
#define NROWS   (BATCH * SEQ)   // 4096
#define E2      (2 * D_INNER)   // 4096

// ---------------------------------------------------------------- LayerNorm
__global__ __launch_bounds__(256) void ln_kernel(const float* __restrict__ x,
                                                 const float* __restrict__ w,
                                                 const float* __restrict__ b,
                                                 float* __restrict__ xn) {
    int row = blockIdx.x;
    int tid = threadIdx.x;
    const float4* xr = (const float4*)(x + (size_t)row * D_MODEL);
    float4 v = xr[tid];                      // 256 threads x float4 = 1024
    float s  = v.x + v.y + v.z + v.w;
    float s2 = v.x * v.x + v.y * v.y + v.z * v.z + v.w * v.w;
#pragma unroll
    for (int o = 32; o > 0; o >>= 1) {
        s  += __shfl_down(s,  o, 64);
        s2 += __shfl_down(s2, o, 64);
    }
    __shared__ float red[2][4];
    int wid = tid >> 6, lane = tid & 63;
    if (lane == 0) { red[0][wid] = s; red[1][wid] = s2; }
    __syncthreads();
    s  = red[0][0] + red[0][1] + red[0][2] + red[0][3];
    s2 = red[1][0] + red[1][1] + red[1][2] + red[1][3];
    float mu  = s * (1.0f / D_MODEL);
    float var = s2 * (1.0f / D_MODEL) - mu * mu;
    float rs  = rsqrtf(var + 1e-5f);
    float4 wv = ((const float4*)w)[tid];
    float4 bv = ((const float4*)b)[tid];
    float4 o;
    o.x = (v.x - mu) * rs * wv.x + bv.x;
    o.y = (v.y - mu) * rs * wv.y + bv.y;
    o.z = (v.z - mu) * rs * wv.z + bv.z;
    o.w = (v.w - mu) * rs * wv.w + bv.w;
    ((float4*)(xn + (size_t)row * D_MODEL))[tid] = o;
}

// ------------------------------------------------- fp32 tiled GEMM  C = A·B^T
// A [M][K] row-major (lda), Bw [N][K] row-major (ldb): C[m][n] = dot(A[m,:], Bw[n,:])
// 64x64 tile per block, 256 threads, 4x4 micro-tile per thread, BK=16.
template <bool ADD_RES>
__global__ __launch_bounds__(256) void gemm_tn(const float* __restrict__ A, int lda,
                                               const float* __restrict__ Bw, int ldb,
                                               float* __restrict__ C, int ldc,
                                               const float* __restrict__ res, int K) {
    __shared__ float sa[16][68];   // [k][m], +4 pad keeps 16B alignment, 2-way max
    __shared__ float sb[16][68];   // [k][n]
    int tid = threadIdx.x;
    int m0 = blockIdx.y * 64, n0 = blockIdx.x * 64;
    int lr = tid >> 2;             // 0..63 row within tile
    int lk = (tid & 3) * 4;        // 0,4,8,12 k within BK
    int ty = tid >> 4, tx = tid & 15;
    float acc[4][4] = {};
    for (int k0 = 0; k0 < K; k0 += 16) {
        float4 av = *(const float4*)(A  + (size_t)(m0 + lr) * lda + k0 + lk);
        float4 bv = *(const float4*)(Bw + (size_t)(n0 + lr) * ldb + k0 + lk);
        __syncthreads();           // protect previous iteration's reads
        sa[lk + 0][lr] = av.x; sa[lk + 1][lr] = av.y; sa[lk + 2][lr] = av.z; sa[lk + 3][lr] = av.w;
        sb[lk + 0][lr] = bv.x; sb[lk + 1][lr] = bv.y; sb[lk + 2][lr] = bv.z; sb[lk + 3][lr] = bv.w;
        __syncthreads();
#pragma unroll
        for (int kk = 0; kk < 16; ++kk) {
            float4 a = *(const float4*)&sa[kk][ty * 4];
            float4 b = *(const float4*)&sb[kk][tx * 4];
            float ar[4] = {a.x, a.y, a.z, a.w};
            float br[4] = {b.x, b.y, b.z, b.w};
#pragma unroll
            for (int i = 0; i < 4; ++i)
#pragma unroll
                for (int j = 0; j < 4; ++j) acc[i][j] += ar[i] * br[j];
        }
    }
#pragma unroll
    for (int i = 0; i < 4; ++i) {
        int m = m0 + ty * 4 + i;
        float4 o = {acc[i][0], acc[i][1], acc[i][2], acc[i][3]};
        float* cp = C + (size_t)m * ldc + n0 + tx * 4;
        if (ADD_RES) {
            float4 r = *(const float4*)(res + (size_t)m * ldc + n0 + tx * 4);
            o.x += r.x; o.y += r.y; o.z += r.z; o.w += r.w;
        }
        *(float4*)cp = o;
    }
}

// --------------------------------------------- depthwise causal conv4 + SiLU
// x_b[b][t][d] lives in xz[(b*SEQ+t)*E2 + d] (d < D_INNER). Output xc[b][t][d].
__global__ __launch_bounds__(256) void conv_silu(const float* __restrict__ xz,
                                                 const float* __restrict__ cw,
                                                 const float* __restrict__ cb,
                                                 float* __restrict__ xc) {
    const int TCH = 128;
    int d  = blockIdx.x * 256 + threadIdx.x;
    int t0 = blockIdx.y * TCH;
    int bb = blockIdx.z;
    const float* xp = xz + (size_t)bb * SEQ * E2 + d;
    float w0 = cw[d * 4 + 0], w1 = cw[d * 4 + 1], w2 = cw[d * 4 + 2], w3 = cw[d * 4 + 3];
    float bias = cb[d];
    float xm3 = (t0 >= 3) ? xp[(size_t)(t0 - 3) * E2] : 0.0f;
    float xm2 = (t0 >= 2) ? xp[(size_t)(t0 - 2) * E2] : 0.0f;
    float xm1 = (t0 >= 1) ? xp[(size_t)(t0 - 1) * E2] : 0.0f;
    float* op = xc + ((size_t)bb * SEQ + t0) * D_INNER + d;
    for (int t = t0; t < t0 + TCH; ++t) {
        float xt = xp[(size_t)t * E2];
        float a = w0 * xm3 + w1 * xm2 + w2 * xm1 + w3 * xt + bias;
        a = a / (1.0f + __expf(-a));          // SiLU
        *op = a;
        op += D_INNER;
        xm3 = xm2; xm2 = xm1; xm1 = xt;
    }
}

// ----------------------------------------------- x-projection: ssm = xc·W_x^T
// one block per row m; 33 outputs; W_x is [33][D_INNER], L2-resident.
__global__ __launch_bounds__(256) void ssm_proj(const float* __restrict__ xc,
                                                const float* __restrict__ Wx,
                                                float* __restrict__ ssm) {
    int m = blockIdx.x;
    int tid = threadIdx.x;
    const float* xr = xc + (size_t)m * D_INNER;
    float acc[33];
#pragma unroll
    for (int e = 0; e < 33; ++e) acc[e] = 0.0f;
    for (int k = tid; k < D_INNER; k += 256) {
        float xv = xr[k];
#pragma unroll
        for (int e = 0; e < 33; ++e) acc[e] += xv * Wx[e * D_INNER + k];
    }
#pragma unroll
    for (int e = 0; e < 33; ++e) {
        float v = acc[e];
#pragma unroll
        for (int o = 32; o > 0; o >>= 1) v += __shfl_down(v, o, 64);
        acc[e] = v;
    }
    __shared__ float red[4][33];
    int wid = tid >> 6, lane = tid & 63;
    if (lane == 0) {
#pragma unroll
        for (int e = 0; e < 33; ++e) red[wid][e] = acc[e];
    }
    __syncthreads();
    if (tid < 33) {
        ssm[(size_t)m * 33 + tid] =
            red[0][tid] + red[1][tid] + red[2][tid] + red[3][tid];
    }
}

// --------------------------------------------------------- selective scan
// thread = (channel c, state n); 16 channels x 16 states per block.
__global__ __launch_bounds__(256) void scan_kernel(const float* __restrict__ ssm,
                                                   const float* __restrict__ xc,
                                                   const float* __restrict__ xz,
                                                   const float* __restrict__ Wdt,
                                                   const float* __restrict__ bdt,
                                                   const float* __restrict__ Alog,
                                                   const float* __restrict__ Dp,
                                                   float* __restrict__ y) {
    int bb = blockIdx.y;
    int d0 = blockIdx.x * 16;
    int tid = threadIdx.x;
    int n = tid & 15, c = tid >> 4;
    int d = d0 + c;
    float A   = -__expf(Alog[d * D_STATE + n]);
    float wdt = Wdt[d], bd = bdt[d], Dd = Dp[d];
    float h = 0.0f;
    const int TCH = 64;
    __shared__ float s_ssm[TCH][33];
    __shared__ float s_x[TCH][16];
    __shared__ float s_z[TCH][16];
    const float* ssm_b = ssm + (size_t)bb * SEQ * 33;
    const float* x_b   = xc  + (size_t)bb * SEQ * D_INNER;
    const float* z_b   = xz  + (size_t)bb * SEQ * E2 + D_INNER;
    float* y_b = y + (size_t)bb * SEQ * D_INNER;
    for (int t0 = 0; t0 < SEQ; t0 += TCH) {
        __syncthreads();
        for (int i = tid; i < TCH * 33; i += 256) {
            int tt = i / 33, e = i % 33;
            s_ssm[tt][e] = ssm_b[(size_t)(t0 + tt) * 33 + e];
        }
        for (int i = tid; i < TCH * 16; i += 256) {
            int tt = i >> 4, cc = i & 15;
            s_x[tt][cc] = x_b[(size_t)(t0 + tt) * D_INNER + d0 + cc];
            s_z[tt][cc] = z_b[(size_t)(t0 + tt) * E2 + d0 + cc];
        }
        __syncthreads();
        for (int tt = 0; tt < TCH; ++tt) {
            float draw = s_ssm[tt][0];
            float Bn   = s_ssm[tt][1 + n];
            float Cn   = s_ssm[tt][17 + n];
            float xv   = s_x[tt][c];
            float u = draw * wdt + bd;
            float delta = (u > 20.0f) ? u : log1pf(__expf(u));
            float dA = __expf(delta * A);
            h = dA * h + (delta * Bn) * xv;
            float p = h * Cn;
            p += __shfl_xor(p, 1, 64);
            p += __shfl_xor(p, 2, 64);
            p += __shfl_xor(p, 4, 64);
            p += __shfl_xor(p, 8, 64);
            if (n == 0) {
                float zv = s_z[tt][c];
                float yv = (p + xv * Dd) * (zv / (1.0f + __expf(-zv)));
                y_b[(size_t)(t0 + tt) * D_INNER + d] = yv;
            }
        }
    }
}

extern "C" void kernel_launch(void* const* d_in, const int* in_sizes, int n_in,
                              void* d_out, int out_size, void* d_ws, size_t ws_size,
                              hipStream_t stream) {
    const float* x      = (const float*)d_in[0];
    const float* ln_w   = (const float*)d_in[1];
    const float* ln_b   = (const float*)d_in[2];
    const float* W_in   = (const float*)d_in[3];
    const float* conv_w = (const float*)d_in[4];
    const float* conv_b = (const float*)d_in[5];
    const float* W_x    = (const float*)d_in[6];
    const float* W_dt   = (const float*)d_in[7];
    const float* b_dt   = (const float*)d_in[8];
    const float* A_log  = (const float*)d_in[9];
    const float* Dp     = (const float*)d_in[10];
    const float* W_out  = (const float*)d_in[11];
    float* out = (float*)d_out;

    float* xn   = (float*)d_ws;                         // 4096*1024
    float* xz   = xn + (size_t)NROWS * D_MODEL;         // 4096*4096
    float* xc   = xz + (size_t)NROWS * E2;              // 4096*2048
    float* ssmb = xc + (size_t)NROWS * D_INNER;         // 4096*33
    float* y    = xc;   // alias: scan stages x in LDS before overwriting

    ln_kernel<<<NROWS, 256, 0, stream>>>(x, ln_w, ln_b, xn);
    gemm_tn<false><<<dim3(E2 / 64, NROWS / 64), 256, 0, stream>>>(
        xn, D_MODEL, W_in, D_MODEL, xz, E2, nullptr, D_MODEL);
    conv_silu<<<dim3(D_INNER / 256, SEQ / 128, BATCH), 256, 0, stream>>>(
        xz, conv_w, conv_b, xc);
    ssm_proj<<<NROWS, 256, 0, stream>>>(xc, W_x, ssmb);
    scan_kernel<<<dim3(D_INNER / 16, BATCH), 256, 0, stream>>>(
        ssmb, xc, xz, W_dt, b_dt, A_log, Dp, y);
    gemm_tn<true><<<dim3(D_MODEL / 64, NROWS / 64), 256, 0, stream>>>(
        y, D_INNER, W_out, D_INNER, out, D_MODEL, x, D_INNER);
}

// Round 2
// 867.459 us; speedup vs baseline: 2.2122x; 2.2122x over previous
//
#include <hip/hip_runtime.h>
#include <math.h>

#define D_MODEL 1024
#define D_STATE 16
#define D_CONV  4
#define D_INNER 2048
#define BATCH   2
#define SEQ     2048
#define NROWS   (BATCH * SEQ)   // 4096
#define E2      (2 * D_INNER)   // 4096
#define CL      64              // scan chunk length
#define NC      (SEQ / CL)      // 32 chunks

// ---------------------------------------------------------------- LayerNorm
__global__ __launch_bounds__(256) void ln_kernel(const float* __restrict__ x,
                                                 const float* __restrict__ w,
                                                 const float* __restrict__ b,
                                                 float* __restrict__ xn) {
    int row = blockIdx.x;
    int tid = threadIdx.x;
    const float4* xr = (const float4*)(x + (size_t)row * D_MODEL);
    float4 v = xr[tid];                      // 256 threads x float4 = 1024
    float s  = v.x + v.y + v.z + v.w;
    float s2 = v.x * v.x + v.y * v.y + v.z * v.z + v.w * v.w;
#pragma unroll
    for (int o = 32; o > 0; o >>= 1) {
        s  += __shfl_down(s,  o, 64);
        s2 += __shfl_down(s2, o, 64);
    }
    __shared__ float red[2][4];
    int wid = tid >> 6, lane = tid & 63;
    if (lane == 0) { red[0][wid] = s; red[1][wid] = s2; }
    __syncthreads();
    s  = red[0][0] + red[0][1] + red[0][2] + red[0][3];
    s2 = red[1][0] + red[1][1] + red[1][2] + red[1][3];
    float mu  = s * (1.0f / D_MODEL);
    float var = s2 * (1.0f / D_MODEL) - mu * mu;
    float rs  = rsqrtf(var + 1e-5f);
    float4 wv = ((const float4*)w)[tid];
    float4 bv = ((const float4*)b)[tid];
    float4 o;
    o.x = (v.x - mu) * rs * wv.x + bv.x;
    o.y = (v.y - mu) * rs * wv.y + bv.y;
    o.z = (v.z - mu) * rs * wv.z + bv.z;
    o.w = (v.w - mu) * rs * wv.w + bv.w;
    ((float4*)(xn + (size_t)row * D_MODEL))[tid] = o;
}

// ------------------------------------------------- fp32 tiled GEMM  C = A·B^T
template <bool ADD_RES>
__global__ __launch_bounds__(256) void gemm_tn(const float* __restrict__ A, int lda,
                                               const float* __restrict__ Bw, int ldb,
                                               float* __restrict__ C, int ldc,
                                               const float* __restrict__ res, int K) {
    __shared__ float sa[16][68];
    __shared__ float sb[16][68];
    int tid = threadIdx.x;
    int m0 = blockIdx.y * 64, n0 = blockIdx.x * 64;
    int lr = tid >> 2;
    int lk = (tid & 3) * 4;
    int ty = tid >> 4, tx = tid & 15;
    float acc[4][4] = {};
    for (int k0 = 0; k0 < K; k0 += 16) {
        float4 av = *(const float4*)(A  + (size_t)(m0 + lr) * lda + k0 + lk);
        float4 bv = *(const float4*)(Bw + (size_t)(n0 + lr) * ldb + k0 + lk);
        __syncthreads();
        sa[lk + 0][lr] = av.x; sa[lk + 1][lr] = av.y; sa[lk + 2][lr] = av.z; sa[lk + 3][lr] = av.w;
        sb[lk + 0][lr] = bv.x; sb[lk + 1][lr] = bv.y; sb[lk + 2][lr] = bv.z; sb[lk + 3][lr] = bv.w;
        __syncthreads();
#pragma unroll
        for (int kk = 0; kk < 16; ++kk) {
            float4 a = *(const float4*)&sa[kk][ty * 4];
            float4 b = *(const float4*)&sb[kk][tx * 4];
            float ar[4] = {a.x, a.y, a.z, a.w};
            float br[4] = {b.x, b.y, b.z, b.w};
#pragma unroll
            for (int i = 0; i < 4; ++i)
#pragma unroll
                for (int j = 0; j < 4; ++j) acc[i][j] += ar[i] * br[j];
        }
    }
#pragma unroll
    for (int i = 0; i < 4; ++i) {
        int m = m0 + ty * 4 + i;
        float4 o = {acc[i][0], acc[i][1], acc[i][2], acc[i][3]};
        float* cp = C + (size_t)m * ldc + n0 + tx * 4;
        if (ADD_RES) {
            float4 r = *(const float4*)(res + (size_t)m * ldc + n0 + tx * 4);
            o.x += r.x; o.y += r.y; o.z += r.z; o.w += r.w;
        }
        *(float4*)cp = o;
    }
}

// --------------------------------------------- depthwise causal conv4 + SiLU
__global__ __launch_bounds__(256) void conv_silu(const float* __restrict__ xz,
                                                 const float* __restrict__ cw,
                                                 const float* __restrict__ cb,
                                                 float* __restrict__ xc) {
    const int TCH = 128;
    int d  = blockIdx.x * 256 + threadIdx.x;
    int t0 = blockIdx.y * TCH;
    int bb = blockIdx.z;
    const float* xp = xz + (size_t)bb * SEQ * E2 + d;
    float w0 = cw[d * 4 + 0], w1 = cw[d * 4 + 1], w2 = cw[d * 4 + 2], w3 = cw[d * 4 + 3];
    float bias = cb[d];
    float xm3 = (t0 >= 3) ? xp[(size_t)(t0 - 3) * E2] : 0.0f;
    float xm2 = (t0 >= 2) ? xp[(size_t)(t0 - 2) * E2] : 0.0f;
    float xm1 = (t0 >= 1) ? xp[(size_t)(t0 - 1) * E2] : 0.0f;
    float* op = xc + ((size_t)bb * SEQ + t0) * D_INNER + d;
    for (int t = t0; t < t0 + TCH; ++t) {
        float xt = xp[(size_t)t * E2];
        float a = w0 * xm3 + w1 * xm2 + w2 * xm1 + w3 * xt + bias;
        a = a / (1.0f + __expf(-a));          // SiLU
        *op = a;
        op += D_INNER;
        xm3 = xm2; xm2 = xm1; xm1 = xt;
    }
}

// ----------------------------------------------- x-projection: ssm = xc·W_x^T
__global__ __launch_bounds__(256) void ssm_proj(const float* __restrict__ xc,
                                                const float* __restrict__ Wx,
                                                float* __restrict__ ssm) {
    int m = blockIdx.x;
    int tid = threadIdx.x;
    const float* xr = xc + (size_t)m * D_INNER;
    float acc[33];
#pragma unroll
    for (int e = 0; e < 33; ++e) acc[e] = 0.0f;
    for (int k = tid; k < D_INNER; k += 256) {
        float xv = xr[k];
#pragma unroll
        for (int e = 0; e < 33; ++e) acc[e] += xv * Wx[e * D_INNER + k];
    }
#pragma unroll
    for (int e = 0; e < 33; ++e) {
        float v = acc[e];
#pragma unroll
        for (int o = 32; o > 0; o >>= 1) v += __shfl_down(v, o, 64);
        acc[e] = v;
    }
    __shared__ float red[4][33];
    int wid = tid >> 6, lane = tid & 63;
    if (lane == 0) {
#pragma unroll
        for (int e = 0; e < 33; ++e) red[wid][e] = acc[e];
    }
    __syncthreads();
    if (tid < 33) {
        ssm[(size_t)m * 33 + tid] =
            red[0][tid] + red[1][tid] + red[2][tid] + red[3][tid];
    }
}

// ============================ chunked parallel scan ========================
// Linear recurrence h_t = dA_t*h + dB_t*x_t is associative. Split SEQ into NC
// chunks of CL. Thread = one channel d, holds all 16 states in registers.
// dA_n = exp(delta*A_n) => chunk decay = exp(A_n * sum(delta)) — track Ssum.

// pass1: per (b,chunk,d): local h[16] from h=0, and Ssum.
__global__ __launch_bounds__(256) void scan_pass1(const float* __restrict__ ssm,
                                                  const float* __restrict__ xc,
                                                  const float* __restrict__ Wdt,
                                                  const float* __restrict__ bdt,
                                                  const float* __restrict__ Alog,
                                                  float* __restrict__ chunkF,
                                                  float* __restrict__ chunkS) {
    int bb = blockIdx.z, c = blockIdx.y;
    int d = blockIdx.x * 256 + threadIdx.x;
    int tid = threadIdx.x;
    __shared__ float s_d[CL];
    __shared__ float s_B[CL][16];
    __shared__ float s_C[CL][16];   // unused here but same staging code as pass3
    const float* sp = ssm + ((size_t)bb * SEQ + (size_t)c * CL) * 33;
    for (int i = tid; i < CL * 33; i += 256) {
        int t = i / 33, e = i % 33;
        float v = sp[i];
        if (e == 0) s_d[t] = v;
        else if (e < 17) s_B[t][e - 1] = v;
        else s_C[t][e - 17] = v;
    }
    float A[16];
    {
        const float4* Ap = (const float4*)(Alog + (size_t)d * 16);
#pragma unroll
        for (int q = 0; q < 4; ++q) {
            float4 v = Ap[q];
            A[q * 4 + 0] = -__expf(v.x); A[q * 4 + 1] = -__expf(v.y);
            A[q * 4 + 2] = -__expf(v.z); A[q * 4 + 3] = -__expf(v.w);
        }
    }
    float wdt = Wdt[d], bd = bdt[d];
    __syncthreads();
    const float* xp = xc + ((size_t)bb * SEQ + (size_t)c * CL) * D_INNER + d;
    float h[16];
#pragma unroll
    for (int n = 0; n < 16; ++n) h[n] = 0.f;
    float Ssum = 0.f;
    float xv_next = xp[0];
    for (int t = 0; t < CL; ++t) {
        float xv = xv_next;
        if (t + 1 < CL) xv_next = xp[(size_t)(t + 1) * D_INNER];
        float u = s_d[t] * wdt + bd;
        float e = __expf(u);
        float delta = (u > 20.f) ? u : __logf(1.f + e);
        Ssum += delta;
        float dx = delta * xv;
        const float4* Bp = (const float4*)s_B[t];
#pragma unroll
        for (int q = 0; q < 4; ++q) {
            float4 B4 = Bp[q];
            float bq[4] = {B4.x, B4.y, B4.z, B4.w};
#pragma unroll
            for (int j = 0; j < 4; ++j) {
                int n = q * 4 + j;
                float r = __expf(delta * A[n]);
                h[n] = r * h[n] + dx * bq[j];
            }
        }
    }
    size_t base = ((size_t)bb * NC + c) * 16;
#pragma unroll
    for (int n = 0; n < 16; ++n)
        chunkF[(base + n) * D_INNER + d] = h[n];   // [b][c][n][d] coalesced
    chunkS[((size_t)bb * NC + c) * D_INNER + d] = Ssum;
}

// pass2: combine across chunks, in place: chunkF becomes h_init per chunk.
// grid (D_INNER/256, 16 n, BATCH); thread owns (b,d,n), loops c.
__global__ __launch_bounds__(256) void scan_pass2(const float* __restrict__ Alog,
                                                  const float* __restrict__ chunkS,
                                                  float* __restrict__ chunkF) {
    int d  = blockIdx.x * 256 + threadIdx.x;
    int n  = blockIdx.y;
    int bb = blockIdx.z;
    float A = -__expf(Alog[(size_t)d * 16 + n]);
    float h = 0.f;
    float F = chunkF[(((size_t)bb * NC) * 16 + n) * D_INNER + d];
    float S = chunkS[((size_t)bb * NC) * D_INNER + d];
    for (int c = 0; c < NC; ++c) {
        float Fn = 0.f, Sn = 0.f;
        if (c + 1 < NC) {   // prefetch next chunk record
            Fn = chunkF[(((size_t)bb * NC + c + 1) * 16 + n) * D_INNER + d];
            Sn = chunkS[((size_t)bb * NC + c + 1) * D_INNER + d];
        }
        chunkF[(((size_t)bb * NC + c) * 16 + n) * D_INNER + d] = h;  // h_init[c]
        h = __expf(A * S) * h + F;
        F = Fn; S = Sn;
    }
}

// pass3: recompute recurrence seeded with h_init, emit y = (h·C + x·D)*silu(z).
// y may alias xc: each thread reads x[t][d] (one step ahead) before writing y[t][d].
__global__ __launch_bounds__(256) void scan_pass3(const float* __restrict__ ssm,
                                                  const float* __restrict__ xc,
                                                  const float* __restrict__ xz,
                                                  const float* __restrict__ Wdt,
                                                  const float* __restrict__ bdt,
                                                  const float* __restrict__ Alog,
                                                  const float* __restrict__ Dp,
                                                  const float* __restrict__ hinit,
                                                  float* __restrict__ y) {
    int bb = blockIdx.z, c = blockIdx.y;
    int d = blockIdx.x * 256 + threadIdx.x;
    int tid = threadIdx.x;
    __shared__ float s_d[CL];
    __shared__ float s_B[CL][16];
    __shared__ float s_C[CL][16];
    const float* sp = ssm + ((size_t)bb * SEQ + (size_t)c * CL) * 33;
    for (int i = tid; i < CL * 33; i += 256) {
        int t = i / 33, e = i % 33;
        float v = sp[i];
        if (e == 0) s_d[t] = v;
        else if (e < 17) s_B[t][e - 1] = v;
        else s_C[t][e - 17] = v;
    }
    float A[16];
    {
        const float4* Ap = (const float4*)(Alog + (size_t)d * 16);
#pragma unroll
        for (int q = 0; q < 4; ++q) {
            float4 v = Ap[q];
            A[q * 4 + 0] = -__expf(v.x); A[q * 4 + 1] = -__expf(v.y);
            A[q * 4 + 2] = -__expf(v.z); A[q * 4 + 3] = -__expf(v.w);
        }
    }
    float wdt = Wdt[d], bd = bdt[d], Dd = Dp[d];
    size_t base = ((size_t)bb * NC + c) * 16;
    float h[16];
#pragma unroll
    for (int n = 0; n < 16; ++n)
        h[n] = hinit[(base + n) * D_INNER + d];
    __syncthreads();
    const float* xp = xc + ((size_t)bb * SEQ + (size_t)c * CL) * D_INNER + d;
    const float* zp = xz + ((size_t)bb * SEQ + (size_t)c * CL) * E2 + D_INNER + d;
    float* yp = y + ((size_t)bb * SEQ + (size_t)c * CL) * D_INNER + d;
    float xv_next = xp[0];
    float zv_next = zp[0];
    for (int t = 0; t < CL; ++t) {
        float xv = xv_next, zv = zv_next;
        if (t + 1 < CL) {
            xv_next = xp[(size_t)(t + 1) * D_INNER];
            zv_next = zp[(size_t)(t + 1) * E2];
        }
        float u = s_d[t] * wdt + bd;
        float e = __expf(u);
        float delta = (u > 20.f) ? u : __logf(1.f + e);
        float dx = delta * xv;
        const float4* Bp = (const float4*)s_B[t];
        const float4* Cp = (const float4*)s_C[t];
        float p0 = 0.f, p1 = 0.f;
#pragma unroll
        for (int q = 0; q < 4; ++q) {
            float4 B4 = Bp[q];
            float4 C4 = Cp[q];
            float bq[4] = {B4.x, B4.y, B4.z, B4.w};
            float cq[4] = {C4.x, C4.y, C4.z, C4.w};
#pragma unroll
            for (int j = 0; j < 4; ++j) {
                int n = q * 4 + j;
                float r = __expf(delta * A[n]);
                h[n] = r * h[n] + dx * bq[j];
                if (j & 1) p1 += h[n] * cq[j];
                else       p0 += h[n] * cq[j];
            }
        }
        float pv = p0 + p1 + xv * Dd;
        float yv = pv * (zv / (1.f + __expf(-zv)));
        yp[(size_t)t * D_INNER] = yv;
    }
}

extern "C" void kernel_launch(void* const* d_in, const int* in_sizes, int n_in,
                              void* d_out, int out_size, void* d_ws, size_t ws_size,
                              hipStream_t stream) {
    const float* x      = (const float*)d_in[0];
    const float* ln_w   = (const float*)d_in[1];
    const float* ln_b   = (const float*)d_in[2];
    const float* W_in   = (const float*)d_in[3];
    const float* conv_w = (const float*)d_in[4];
    const float* conv_b = (const float*)d_in[5];
    const float* W_x    = (const float*)d_in[6];
    const float* W_dt   = (const float*)d_in[7];
    const float* b_dt   = (const float*)d_in[8];
    const float* A_log  = (const float*)d_in[9];
    const float* Dp     = (const float*)d_in[10];
    const float* W_out  = (const float*)d_in[11];
    float* out = (float*)d_out;

    float* xn   = (float*)d_ws;                         // 4096*1024 (16.8MB)
    float* xz   = xn + (size_t)NROWS * D_MODEL;         // 4096*4096
    float* xc   = xz + (size_t)NROWS * E2;              // 4096*2048
    float* ssmb = xc + (size_t)NROWS * D_INNER;         // 4096*33
    // chunk records alias xn (dead after gemm1):
    //   chunkF [b][c][n][d] = 2*32*16*2048 = 2.10M floats, chunkS 0.13M — fits in xn's 4.19M
    float* chunkF = xn;
    float* chunkS = xn + (size_t)BATCH * NC * 16 * D_INNER;
    float* y = xc;   // pass3 reads x[t][d] before writing y[t][d] (same thread)

    ln_kernel<<<NROWS, 256, 0, stream>>>(x, ln_w, ln_b, xn);
    gemm_tn<false><<<dim3(E2 / 64, NROWS / 64), 256, 0, stream>>>(
        xn, D_MODEL, W_in, D_MODEL, xz, E2, nullptr, D_MODEL);
    conv_silu<<<dim3(D_INNER / 256, SEQ / 128, BATCH), 256, 0, stream>>>(
        xz, conv_w, conv_b, xc);
    ssm_proj<<<NROWS, 256, 0, stream>>>(xc, W_x, ssmb);
    scan_pass1<<<dim3(D_INNER / 256, NC, BATCH), 256, 0, stream>>>(
        ssmb, xc, W_dt, b_dt, A_log, chunkF, chunkS);
    scan_pass2<<<dim3(D_INNER / 256, D_STATE, BATCH), 256, 0, stream>>>(
        A_log, chunkS, chunkF);
    scan_pass3<<<dim3(D_INNER / 256, NC, BATCH), 256, 0, stream>>>(
        ssmb, xc, xz, W_dt, b_dt, A_log, Dp, chunkF, y);
    gemm_tn<true><<<dim3(D_MODEL / 64, NROWS / 64), 256, 0, stream>>>(
        y, D_INNER, W_out, D_INNER, out, D_MODEL, x, D_INNER);
}

// Round 3
// 289.949 us; speedup vs baseline: 6.6184x; 2.9918x over previous
//
#include <hip/hip_runtime.h>
#include <math.h>

#define D_MODEL 1024
#define D_STATE 16
#define D_CONV  4
#define D_INNER 2048
#define BATCH   2
#define SEQ     2048
#define NROWS   (BATCH * SEQ)   // 4096
#define E2      (2 * D_INNER)   // 4096
#define CL      64              // scan chunk length
#define NC      (SEQ / CL)      // 32 chunks

typedef unsigned short u16;
typedef __attribute__((ext_vector_type(8))) short bf16x8_t;   // 8 bf16 = 4 VGPR
typedef __attribute__((ext_vector_type(4))) float f32x4_t;

static __device__ __forceinline__ u16 f2bf(float f) {
    unsigned int u = __builtin_bit_cast(unsigned int, f);
    unsigned int r = (u + 0x7fffu + ((u >> 16) & 1u)) >> 16;   // RNE
    return (u16)r;
}
static __device__ __forceinline__ float bf2f(u16 u) {
    return __builtin_bit_cast(float, ((unsigned int)u) << 16);
}

// ---------------------------------------------------- fp32 -> bf16 converter
__global__ __launch_bounds__(256) void f2bf_kernel(const float4* __restrict__ in,
                                                   ushort4* __restrict__ out, int n4) {
    int i = blockIdx.x * 256 + threadIdx.x;
    if (i < n4) {
        float4 v = in[i];
        ushort4 o;
        o.x = f2bf(v.x); o.y = f2bf(v.y); o.z = f2bf(v.z); o.w = f2bf(v.w);
        out[i] = o;
    }
}

// ---------------------------------------------------------------- LayerNorm
__global__ __launch_bounds__(256) void ln_kernel(const float* __restrict__ x,
                                                 const float* __restrict__ w,
                                                 const float* __restrict__ b,
                                                 u16* __restrict__ xn) {
    int row = blockIdx.x;
    int tid = threadIdx.x;
    const float4* xr = (const float4*)(x + (size_t)row * D_MODEL);
    float4 v = xr[tid];
    float s  = v.x + v.y + v.z + v.w;
    float s2 = v.x * v.x + v.y * v.y + v.z * v.z + v.w * v.w;
#pragma unroll
    for (int o = 32; o > 0; o >>= 1) {
        s  += __shfl_down(s,  o, 64);
        s2 += __shfl_down(s2, o, 64);
    }
    __shared__ float red[2][4];
    int wid = tid >> 6, lane = tid & 63;
    if (lane == 0) { red[0][wid] = s; red[1][wid] = s2; }
    __syncthreads();
    s  = red[0][0] + red[0][1] + red[0][2] + red[0][3];
    s2 = red[1][0] + red[1][1] + red[1][2] + red[1][3];
    float mu  = s * (1.0f / D_MODEL);
    float var = s2 * (1.0f / D_MODEL) - mu * mu;
    float rs  = rsqrtf(var + 1e-5f);
    float4 wv = ((const float4*)w)[tid];
    float4 bv = ((const float4*)b)[tid];
    ushort4 o;
    o.x = f2bf((v.x - mu) * rs * wv.x + bv.x);
    o.y = f2bf((v.y - mu) * rs * wv.y + bv.y);
    o.z = f2bf((v.z - mu) * rs * wv.z + bv.z);
    o.w = f2bf((v.w - mu) * rs * wv.w + bv.w);
    ((ushort4*)(xn + (size_t)row * D_MODEL))[tid] = o;
}

// --------------------------------------------- bf16 MFMA GEMM  C = A·B^T
// A [M][K] bf16 row-major, Bw [N][K] bf16 row-major. 128x128 tile, BK=32,
// 256 thr = 4 waves (2x2), each wave 64x64 = 4x4 frags of 16x16x32.
template <bool OUT_BF16, bool ADD_RES>
__global__ __launch_bounds__(256) void gemm_mfma(const u16* __restrict__ A, int lda,
                                                 const u16* __restrict__ Bw, int ldb,
                                                 void* __restrict__ Cout, int ldc,
                                                 const float* __restrict__ res, int K) {
    __shared__ u16 sa[128][40];   // stride 40 elems = 80B: read conflicts 2-way (free)
    __shared__ u16 sb[128][40];
    int tid = threadIdx.x;
    int m0 = blockIdx.y * 128, n0 = blockIdx.x * 128;
    int r  = tid >> 1;             // 0..127 staging row
    int hf = (tid & 1) * 16;       // k-half 0/16
    int w  = tid >> 6;
    int wr = (w >> 1) * 64, wc = (w & 1) * 64;
    int lane = tid & 63;
    int fr = lane & 15;            // frag row/col within 16
    int kb = (lane >> 4) * 8;      // frag k base

    f32x4_t acc[4][4];
#pragma unroll
    for (int i = 0; i < 4; ++i)
#pragma unroll
        for (int j = 0; j < 4; ++j) acc[i][j] = (f32x4_t){0.f, 0.f, 0.f, 0.f};

    const u16* Ap = A  + (size_t)(m0 + r) * lda + hf;
    const u16* Bp = Bw + (size_t)(n0 + r) * ldb + hf;

    for (int k0 = 0; k0 < K; k0 += 32) {
        bf16x8_t av0 = *(const bf16x8_t*)(Ap + k0);
        bf16x8_t av1 = *(const bf16x8_t*)(Ap + k0 + 8);
        bf16x8_t bv0 = *(const bf16x8_t*)(Bp + k0);
        bf16x8_t bv1 = *(const bf16x8_t*)(Bp + k0 + 8);
        __syncthreads();           // previous iteration's reads done
        *(bf16x8_t*)&sa[r][hf]     = av0;
        *(bf16x8_t*)&sa[r][hf + 8] = av1;
        *(bf16x8_t*)&sb[r][hf]     = bv0;
        *(bf16x8_t*)&sb[r][hf + 8] = bv1;
        __syncthreads();
        bf16x8_t af[4], bfb[4];
#pragma unroll
        for (int i = 0; i < 4; ++i) {
            af[i]  = *(const bf16x8_t*)&sa[wr + i * 16 + fr][kb];
            bfb[i] = *(const bf16x8_t*)&sb[wc + i * 16 + fr][kb];
        }
#pragma unroll
        for (int i = 0; i < 4; ++i)
#pragma unroll
            for (int j = 0; j < 4; ++j)
                acc[i][j] = __builtin_amdgcn_mfma_f32_16x16x32_bf16(
                    af[i], bfb[j], acc[i][j], 0, 0, 0);
    }

    int mrow0 = m0 + wr + (lane >> 4) * 4;   // C/D: col=lane&15, row=(lane>>4)*4+q
#pragma unroll
    for (int i = 0; i < 4; ++i) {
#pragma unroll
        for (int j = 0; j < 4; ++j) {
            int n = n0 + wc + j * 16 + fr;
#pragma unroll
            for (int q = 0; q < 4; ++q) {
                int m = mrow0 + i * 16 + q;
                float v = acc[i][j][q];
                if (ADD_RES) v += res[(size_t)m * ldc + n];
                if (OUT_BF16) ((u16*)Cout)[(size_t)m * ldc + n] = f2bf(v);
                else          ((float*)Cout)[(size_t)m * ldc + n] = v;
            }
        }
    }
}

// --------------------------------------------- depthwise causal conv4 + SiLU
__global__ __launch_bounds__(256) void conv_silu(const u16* __restrict__ xz,
                                                 const float* __restrict__ cw,
                                                 const float* __restrict__ cb,
                                                 float* __restrict__ xc) {
    const int TCH = 128;
    int d  = blockIdx.x * 256 + threadIdx.x;
    int t0 = blockIdx.y * TCH;
    int bb = blockIdx.z;
    const u16* xp = xz + (size_t)bb * SEQ * E2 + d;
    float w0 = cw[d * 4 + 0], w1 = cw[d * 4 + 1], w2 = cw[d * 4 + 2], w3 = cw[d * 4 + 3];
    float bias = cb[d];
    float xm3 = (t0 >= 3) ? bf2f(xp[(size_t)(t0 - 3) * E2]) : 0.0f;
    float xm2 = (t0 >= 2) ? bf2f(xp[(size_t)(t0 - 2) * E2]) : 0.0f;
    float xm1 = (t0 >= 1) ? bf2f(xp[(size_t)(t0 - 1) * E2]) : 0.0f;
    float* op = xc + ((size_t)bb * SEQ + t0) * D_INNER + d;
    for (int t = t0; t < t0 + TCH; ++t) {
        float xt = bf2f(xp[(size_t)t * E2]);
        float a = w0 * xm3 + w1 * xm2 + w2 * xm1 + w3 * xt + bias;
        a = a / (1.0f + __expf(-a));
        *op = a;
        op += D_INNER;
        xm3 = xm2; xm2 = xm1; xm1 = xt;
    }
}

// ----------------------------------------------- x-projection: ssm = xc·W_x^T
__global__ __launch_bounds__(256) void ssm_proj(const float* __restrict__ xc,
                                                const float* __restrict__ Wx,
                                                float* __restrict__ ssm) {
    int m = blockIdx.x;
    int tid = threadIdx.x;
    const float* xr = xc + (size_t)m * D_INNER;
    float acc[33];
#pragma unroll
    for (int e = 0; e < 33; ++e) acc[e] = 0.0f;
    for (int k = tid; k < D_INNER; k += 256) {
        float xv = xr[k];
#pragma unroll
        for (int e = 0; e < 33; ++e) acc[e] += xv * Wx[e * D_INNER + k];
    }
#pragma unroll
    for (int e = 0; e < 33; ++e) {
        float v = acc[e];
#pragma unroll
        for (int o = 32; o > 0; o >>= 1) v += __shfl_down(v, o, 64);
        acc[e] = v;
    }
    __shared__ float red[4][33];
    int wid = tid >> 6, lane = tid & 63;
    if (lane == 0) {
#pragma unroll
        for (int e = 0; e < 33; ++e) red[wid][e] = acc[e];
    }
    __syncthreads();
    if (tid < 33) {
        ssm[(size_t)m * 33 + tid] =
            red[0][tid] + red[1][tid] + red[2][tid] + red[3][tid];
    }
}

// ============================ chunked parallel scan ========================
__global__ __launch_bounds__(256) void scan_pass1(const float* __restrict__ ssm,
                                                  const float* __restrict__ xc,
                                                  const float* __restrict__ Wdt,
                                                  const float* __restrict__ bdt,
                                                  const float* __restrict__ Alog,
                                                  float* __restrict__ chunkF,
                                                  float* __restrict__ chunkS) {
    int bb = blockIdx.z, c = blockIdx.y;
    int d = blockIdx.x * 256 + threadIdx.x;
    int tid = threadIdx.x;
    __shared__ float s_d[CL];
    __shared__ float s_B[CL][16];
    __shared__ float s_C[CL][16];
    const float* sp = ssm + ((size_t)bb * SEQ + (size_t)c * CL) * 33;
    for (int i = tid; i < CL * 33; i += 256) {
        int t = i / 33, e = i % 33;
        float v = sp[i];
        if (e == 0) s_d[t] = v;
        else if (e < 17) s_B[t][e - 1] = v;
        else s_C[t][e - 17] = v;
    }
    float A[16];
    {
        const float4* Ap = (const float4*)(Alog + (size_t)d * 16);
#pragma unroll
        for (int q = 0; q < 4; ++q) {
            float4 v = Ap[q];
            A[q * 4 + 0] = -__expf(v.x); A[q * 4 + 1] = -__expf(v.y);
            A[q * 4 + 2] = -__expf(v.z); A[q * 4 + 3] = -__expf(v.w);
        }
    }
    float wdt = Wdt[d], bd = bdt[d];
    __syncthreads();
    const float* xp = xc + ((size_t)bb * SEQ + (size_t)c * CL) * D_INNER + d;
    float h[16];
#pragma unroll
    for (int n = 0; n < 16; ++n) h[n] = 0.f;
    float Ssum = 0.f;
    float xv_next = xp[0];
    for (int t = 0; t < CL; ++t) {
        float xv = xv_next;
        if (t + 1 < CL) xv_next = xp[(size_t)(t + 1) * D_INNER];
        float u = s_d[t] * wdt + bd;
        float e = __expf(u);
        float delta = (u > 20.f) ? u : __logf(1.f + e);
        Ssum += delta;
        float dx = delta * xv;
        const float4* Bp = (const float4*)s_B[t];
#pragma unroll
        for (int q = 0; q < 4; ++q) {
            float4 B4 = Bp[q];
            float bq[4] = {B4.x, B4.y, B4.z, B4.w};
#pragma unroll
            for (int j = 0; j < 4; ++j) {
                int n = q * 4 + j;
                float rr = __expf(delta * A[n]);
                h[n] = rr * h[n] + dx * bq[j];
            }
        }
    }
    size_t base = ((size_t)bb * NC + c) * 16;
#pragma unroll
    for (int n = 0; n < 16; ++n)
        chunkF[(base + n) * D_INNER + d] = h[n];
    chunkS[((size_t)bb * NC + c) * D_INNER + d] = Ssum;
}

__global__ __launch_bounds__(256) void scan_pass2(const float* __restrict__ Alog,
                                                  const float* __restrict__ chunkS,
                                                  float* __restrict__ chunkF) {
    int d  = blockIdx.x * 256 + threadIdx.x;
    int n  = blockIdx.y;
    int bb = blockIdx.z;
    float A = -__expf(Alog[(size_t)d * 16 + n]);
    float h = 0.f;
    float F = chunkF[(((size_t)bb * NC) * 16 + n) * D_INNER + d];
    float S = chunkS[((size_t)bb * NC) * D_INNER + d];
    for (int c = 0; c < NC; ++c) {
        float Fn = 0.f, Sn = 0.f;
        if (c + 1 < NC) {
            Fn = chunkF[(((size_t)bb * NC + c + 1) * 16 + n) * D_INNER + d];
            Sn = chunkS[((size_t)bb * NC + c + 1) * D_INNER + d];
        }
        chunkF[(((size_t)bb * NC + c) * 16 + n) * D_INNER + d] = h;
        h = __expf(A * S) * h + F;
        F = Fn; S = Sn;
    }
}

__global__ __launch_bounds__(256) void scan_pass3(const float* __restrict__ ssm,
                                                  const float* __restrict__ xc,
                                                  const u16* __restrict__ xz,
                                                  const float* __restrict__ Wdt,
                                                  const float* __restrict__ bdt,
                                                  const float* __restrict__ Alog,
                                                  const float* __restrict__ Dp,
                                                  const float* __restrict__ hinit,
                                                  u16* __restrict__ y) {
    int bb = blockIdx.z, c = blockIdx.y;
    int d = blockIdx.x * 256 + threadIdx.x;
    int tid = threadIdx.x;
    __shared__ float s_d[CL];
    __shared__ float s_B[CL][16];
    __shared__ float s_C[CL][16];
    const float* sp = ssm + ((size_t)bb * SEQ + (size_t)c * CL) * 33;
    for (int i = tid; i < CL * 33; i += 256) {
        int t = i / 33, e = i % 33;
        float v = sp[i];
        if (e == 0) s_d[t] = v;
        else if (e < 17) s_B[t][e - 1] = v;
        else s_C[t][e - 17] = v;
    }
    float A[16];
    {
        const float4* Ap = (const float4*)(Alog + (size_t)d * 16);
#pragma unroll
        for (int q = 0; q < 4; ++q) {
            float4 v = Ap[q];
            A[q * 4 + 0] = -__expf(v.x); A[q * 4 + 1] = -__expf(v.y);
            A[q * 4 + 2] = -__expf(v.z); A[q * 4 + 3] = -__expf(v.w);
        }
    }
    float wdt = Wdt[d], bd = bdt[d], Dd = Dp[d];
    size_t base = ((size_t)bb * NC + c) * 16;
    float h[16];
#pragma unroll
    for (int n = 0; n < 16; ++n)
        h[n] = hinit[(base + n) * D_INNER + d];
    __syncthreads();
    const float* xp = xc + ((size_t)bb * SEQ + (size_t)c * CL) * D_INNER + d;
    const u16*   zp = xz + ((size_t)bb * SEQ + (size_t)c * CL) * E2 + D_INNER + d;
    u16* yp = y + ((size_t)bb * SEQ + (size_t)c * CL) * D_INNER + d;
    float xv_next = xp[0];
    float zv_next = bf2f(zp[0]);
    for (int t = 0; t < CL; ++t) {
        float xv = xv_next, zv = zv_next;
        if (t + 1 < CL) {
            xv_next = xp[(size_t)(t + 1) * D_INNER];
            zv_next = bf2f(zp[(size_t)(t + 1) * E2]);
        }
        float u = s_d[t] * wdt + bd;
        float e = __expf(u);
        float delta = (u > 20.f) ? u : __logf(1.f + e);
        float dx = delta * xv;
        const float4* Bp = (const float4*)s_B[t];
        const float4* Cp = (const float4*)s_C[t];
        float p0 = 0.f, p1 = 0.f;
#pragma unroll
        for (int q = 0; q < 4; ++q) {
            float4 B4 = Bp[q];
            float4 C4 = Cp[q];
            float bq[4] = {B4.x, B4.y, B4.z, B4.w};
            float cq[4] = {C4.x, C4.y, C4.z, C4.w};
#pragma unroll
            for (int j = 0; j < 4; ++j) {
                int n = q * 4 + j;
                float rr = __expf(delta * A[n]);
                h[n] = rr * h[n] + dx * bq[j];
                if (j & 1) p1 += h[n] * cq[j];
                else       p0 += h[n] * cq[j];
            }
        }
        float pv = p0 + p1 + xv * Dd;
        float yv = pv * (zv / (1.f + __expf(-zv)));
        yp[(size_t)t * D_INNER] = f2bf(yv);
    }
}

extern "C" void kernel_launch(void* const* d_in, const int* in_sizes, int n_in,
                              void* d_out, int out_size, void* d_ws, size_t ws_size,
                              hipStream_t stream) {
    const float* x      = (const float*)d_in[0];
    const float* ln_w   = (const float*)d_in[1];
    const float* ln_b   = (const float*)d_in[2];
    const float* W_in   = (const float*)d_in[3];
    const float* conv_w = (const float*)d_in[4];
    const float* conv_b = (const float*)d_in[5];
    const float* W_x    = (const float*)d_in[6];
    const float* W_dt   = (const float*)d_in[7];
    const float* b_dt   = (const float*)d_in[8];
    const float* A_log  = (const float*)d_in[9];
    const float* Dp     = (const float*)d_in[10];
    const float* W_out  = (const float*)d_in[11];
    float* out = (float*)d_out;

    // ws layout (bytes, all 4KB-aligned chunks): total ~105 MB
    char* wsb = (char*)d_ws;
    const size_t SZ_XN   = (size_t)NROWS * D_MODEL * 2;     // 8.4 MB
    const size_t SZ_WIN  = (size_t)E2 * D_MODEL * 2;        // 8.4 MB
    const size_t SZ_WOUT = (size_t)D_MODEL * D_INNER * 2;   // 4.2 MB
    const size_t SZ_XZ   = (size_t)NROWS * E2 * 2;          // 33.5 MB
    const size_t SZ_XC   = (size_t)NROWS * D_INNER * 4;     // 33.5 MB
    const size_t SZ_SSM  = (size_t)NROWS * 33 * 4;          // 0.54 MB
    u16*   xn_bf   = (u16*)(wsb);
    u16*   Win_bf  = (u16*)(wsb + SZ_XN);
    u16*   Wout_bf = (u16*)(wsb + SZ_XN + SZ_WIN);
    u16*   xz_bf   = (u16*)(wsb + SZ_XN + SZ_WIN + SZ_WOUT);
    float* xc      = (float*)(wsb + SZ_XN + SZ_WIN + SZ_WOUT + SZ_XZ);
    float* ssmb    = (float*)(wsb + SZ_XN + SZ_WIN + SZ_WOUT + SZ_XZ + SZ_XC);
    u16*   y_bf    = (u16*)(wsb + SZ_XN + SZ_WIN + SZ_WOUT + SZ_XZ + SZ_XC + SZ_SSM);
    // chunk records alias xn_bf/Win_bf (dead after gemm1):
    float* chunkF  = (float*)(wsb);            // 8.4 MB exactly fits SZ_XN
    float* chunkS  = (float*)(wsb + SZ_XN);    // 0.52 MB inside SZ_WIN

    f2bf_kernel<<<(E2 * D_MODEL / 4 + 255) / 256, 256, 0, stream>>>(
        (const float4*)W_in, (ushort4*)Win_bf, E2 * D_MODEL / 4);
    f2bf_kernel<<<(D_MODEL * D_INNER / 4 + 255) / 256, 256, 0, stream>>>(
        (const float4*)W_out, (ushort4*)Wout_bf, D_MODEL * D_INNER / 4);
    ln_kernel<<<NROWS, 256, 0, stream>>>(x, ln_w, ln_b, xn_bf);
    gemm_mfma<true, false><<<dim3(E2 / 128, NROWS / 128), 256, 0, stream>>>(
        xn_bf, D_MODEL, Win_bf, D_MODEL, xz_bf, E2, nullptr, D_MODEL);
    conv_silu<<<dim3(D_INNER / 256, SEQ / 128, BATCH), 256, 0, stream>>>(
        xz_bf, conv_w, conv_b, xc);
    ssm_proj<<<NROWS, 256, 0, stream>>>(xc, W_x, ssmb);
    scan_pass1<<<dim3(D_INNER / 256, NC, BATCH), 256, 0, stream>>>(
        ssmb, xc, W_dt, b_dt, A_log, chunkF, chunkS);
    scan_pass2<<<dim3(D_INNER / 256, D_STATE, BATCH), 256, 0, stream>>>(
        A_log, chunkS, chunkF);
    scan_pass3<<<dim3(D_INNER / 256, NC, BATCH), 256, 0, stream>>>(
        ssmb, xc, xz_bf, W_dt, b_dt, A_log, Dp, chunkF, y_bf);
    gemm_mfma<false, true><<<dim3(D_MODEL / 128, NROWS / 128), 256, 0, stream>>>(
        y_bf, D_INNER, Wout_bf, D_INNER, out, D_MODEL, x, D_INNER);
}